// Round 6
// baseline (68.304 us; speedup 1.0000x reference)
//
#include <hip/hip_runtime.h>

#define BSZ 512
#define NN  500
#define KK  100
#define SS  96
#define HIDN 32
#define ROWS (BSZ * NN)       // 256000 output rows
#define NF4  (ROWS * SS / 4)  // 6,144,000 float4 elements
#define F4PR (SS / 4)         // 24 float4 per row
#define NSLOT 12
#define FUSE_BLOCKS 2048
#define FUSE_STRIDE (FUSE_BLOCKS * 256)  // 524288; 12 slots cover NF4

typedef float vf4 __attribute__((ext_vector_type(4)));  // nontemporal-compatible

// ------- kernel 1: prefix-sum of idx_of_node (block 0) + flag clear (all blocks) ----
__global__ __launch_bounds__(512) void prep_kernel(const int* __restrict__ idx_of_node,
                                                   int* __restrict__ offs,
                                                   int* __restrict__ flag) {
    if (blockIdx.x == 0) {
        __shared__ int buf[BSZ];
        int t = threadIdx.x;
        int v = idx_of_node[t];
        buf[t] = v;
        __syncthreads();
        int acc = v;
        for (int d = 1; d < BSZ; d <<= 1) {
            int add = (t >= d) ? buf[t - d] : 0;
            __syncthreads();
            acc += add;
            buf[t] = acc;
            __syncthreads();
        }
        offs[t] = acc - v;  // exclusive prefix
    }
    int4* f4 = reinterpret_cast<int4*>(flag);
    int n4 = ROWS / 4;
    for (int i = blockIdx.x * 512 + threadIdx.x; i < n4; i += gridDim.x * 512)
        f4[i] = make_int4(-1, -1, -1, -1);
}

// ---------------- kernel 2: gather -> MLP -> gate; record flag+gate ----------------
__global__ __launch_bounds__(256) void gate_kernel(
    const float* __restrict__ y, const float* __restrict__ W1,
    const float* __restrict__ b1, const float* __restrict__ W2,
    const float* __restrict__ b2, const float* __restrict__ gumbel,
    const int* __restrict__ krig_idx, const int* __restrict__ offs,
    int* __restrict__ flag, float* __restrict__ gate) {
    __shared__ float4 w1s[SS * HIDN / 4];  // 12 KB, row-major [s][j]
    __shared__ float b1s[HIDN];
    __shared__ float w2s[HIDN * 2];
    __shared__ float b2s[2];
    for (int i = threadIdx.x; i < SS * HIDN / 4; i += 256)
        w1s[i] = reinterpret_cast<const float4*>(W1)[i];
    if (threadIdx.x < HIDN) b1s[threadIdx.x] = b1[threadIdx.x];
    if (threadIdx.x < 2 * HIDN) w2s[threadIdx.x] = W2[threadIdx.x];
    if (threadIdx.x < 2) b2s[threadIdx.x] = b2[threadIdx.x];
    __syncthreads();

    int r = blockIdx.x * 256 + threadIdx.x;
    if (r >= BSZ * KK) return;
    int b = r / KK;
    int node = krig_idx[r];
    const float4* yrow = reinterpret_cast<const float4*>(y + (size_t)(b * NN + node) * SS);

    float h[HIDN];
#pragma unroll
    for (int j = 0; j < HIDN; ++j) h[j] = b1s[j];
#pragma unroll
    for (int s4 = 0; s4 < F4PR; ++s4) {
        float4 v = yrow[s4];
        float vv[4] = {v.x, v.y, v.z, v.w};
        const float4* wbase = &w1s[s4 * 4 * (HIDN / 4)];
#pragma unroll
        for (int q = 0; q < 4; ++q) {
#pragma unroll
            for (int j4 = 0; j4 < HIDN / 4; ++j4) {
                float4 w = wbase[q * (HIDN / 4) + j4];
                h[j4 * 4 + 0] += vv[q] * w.x;
                h[j4 * 4 + 1] += vv[q] * w.y;
                h[j4 * 4 + 2] += vv[q] * w.z;
                h[j4 * 4 + 3] += vv[q] * w.w;
            }
        }
    }
    float l0 = b2s[0], l1 = b2s[1];
#pragma unroll
    for (int j = 0; j < HIDN; ++j) {
        float hr = fmaxf(h[j], 0.0f);
        l0 += hr * w2s[j * 2 + 0];
        l1 += hr * w2s[j * 2 + 1];
    }
    float g0 = gumbel[r * 2 + 0], g1 = gumbel[r * 2 + 1];
    // straight-through hard gumbel: forward value is exactly one-hot {0,1}
    gate[r] = (l1 + g1 > l0 + g0) ? 1.0f : 0.0f;
    flag[offs[b] + node] = r;
}

// ------- kernel 3: fused single-pass output, 12-slot unroll for deep MLP ----------
__global__ __launch_bounds__(256) void fuse_kernel(
    const vf4* __restrict__ x4, const vf4* __restrict__ y4,
    const vf4* __restrict__ mask4, const float* __restrict__ gate,
    const int* __restrict__ flag, const int* __restrict__ krig_idx,
    vf4* __restrict__ out4) {
    const int t = blockIdx.x * 256 + threadIdx.x;

    vf4 xv[NSLOT];
    int fr[NSLOT];
    // phase 1: issue ALL x loads + flag loads (independent; 24 in flight/thread)
#pragma unroll
    for (int k = 0; k < NSLOT; ++k) {
        int idx = t + k * FUSE_STRIDE;
        if (idx < NF4) {
            xv[k] = x4[idx];
            fr[k] = flag[idx / F4PR];
        } else {
            fr[k] = -1;
        }
    }
    // phase 2: kriged overrides (~20% of rows)
#pragma unroll
    for (int k = 0; k < NSLOT; ++k) {
        int r = fr[k];
        if (r >= 0) {
            int idx = t + k * FUSE_STRIDE;
            int row = idx / F4PR;
            int c = idx - row * F4PR;
            int b = r / KK;
            int node = krig_idx[r];
            float g = gate[r];
            vf4 m = mask4[r * F4PR + c];
            vf4 v = y4[(b * NN + node) * F4PR + c];
            xv[k] = g * m * v;
        }
    }
    // phase 3: stores (nontemporal: don't pollute L3, writes stream at fill rate)
#pragma unroll
    for (int k = 0; k < NSLOT; ++k) {
        int idx = t + k * FUSE_STRIDE;
        if (idx < NF4) __builtin_nontemporal_store(xv[k], out4 + idx);
    }
}

extern "C" void kernel_launch(void* const* d_in, const int* in_sizes, int n_in,
                              void* d_out, int out_size, void* d_ws, size_t ws_size,
                              hipStream_t stream) {
    const float* x      = (const float*)d_in[0];
    const float* y      = (const float*)d_in[1];
    const float* W1     = (const float*)d_in[2];
    const float* b1     = (const float*)d_in[3];
    const float* W2     = (const float*)d_in[4];
    const float* b2     = (const float*)d_in[5];
    const float* mask   = (const float*)d_in[6];
    const float* gumbel = (const float*)d_in[7];
    const int* krig_idx = (const int*)d_in[8];
    const int* idx_of_node = (const int*)d_in[9];
    float* out = (float*)d_out;

    int* offs = (int*)d_ws;                       // 512 ints
    int* flag = offs + BSZ;                       // 256000 ints
    float* gate = (float*)(flag + ROWS);          // 51200 floats

    prep_kernel<<<128, 512, 0, stream>>>(idx_of_node, offs, flag);

    int rows = BSZ * KK;
    gate_kernel<<<(rows + 255) / 256, 256, 0, stream>>>(
        y, W1, b1, W2, b2, gumbel, krig_idx, offs, flag, gate);

    fuse_kernel<<<FUSE_BLOCKS, 256, 0, stream>>>(
        reinterpret_cast<const vf4*>(x), reinterpret_cast<const vf4*>(y),
        reinterpret_cast<const vf4*>(mask), gate, flag, krig_idx,
        reinterpret_cast<vf4*>(out));
}

// Round 7
// 59.532 us; speedup vs baseline: 1.1473x; 1.1473x over previous
//
#include <hip/hip_runtime.h>

#define BSZ 512
#define NN  500
#define KK  100
#define SS  96
#define HIDN 32
#define ROWS (BSZ * NN)       // 256000 output rows
#define NF4  (ROWS * SS / 4)  // 6,144,000 float4 elements
#define F4PR (SS / 4)         // 24 float4 per row
#define NSLOT 8
#define FUSE_BLOCKS (NF4 / (256 * NSLOT))  // 3000, exact cover

typedef float vf4 __attribute__((ext_vector_type(4)));

// flag2[row] = {code, mrow}: code==-1 -> copy x row; code==-2 -> zero row (gate=0);
//              code>=0    -> y-row index (gate=1), mrow = mask row index.

// ------- kernel 1: prefix-sum (block 0) + flag2 clear to {-1,*} (all blocks) -------
__global__ __launch_bounds__(512) void prep_kernel(const int* __restrict__ idx_of_node,
                                                   int* __restrict__ offs,
                                                   int4* __restrict__ flag2_4) {
    if (blockIdx.x == 0) {
        __shared__ int buf[BSZ];
        int t = threadIdx.x;
        int v = idx_of_node[t];
        buf[t] = v;
        __syncthreads();
        int acc = v;
        for (int d = 1; d < BSZ; d <<= 1) {
            int add = (t >= d) ? buf[t - d] : 0;
            __syncthreads();
            acc += add;
            buf[t] = acc;
            __syncthreads();
        }
        offs[t] = acc - v;  // exclusive prefix
    }
    // clear 256000 int2 -> 128000 int4 writes of {-1,0,-1,0}
    int n4 = ROWS / 2;  // int4 count = 512000 ints / 4
    for (int i = blockIdx.x * 512 + threadIdx.x; i < n4; i += gridDim.x * 512)
        flag2_4[i] = make_int4(-1, 0, -1, 0);
}

// ---------------- kernel 2: gather -> MLP -> gate; write row descriptor ------------
__global__ __launch_bounds__(256) void gate_kernel(
    const float* __restrict__ y, const float* __restrict__ W1,
    const float* __restrict__ b1, const float* __restrict__ W2,
    const float* __restrict__ b2, const float* __restrict__ gumbel,
    const int* __restrict__ krig_idx, const int* __restrict__ offs,
    int2* __restrict__ flag2) {
    __shared__ float4 w1s[SS * HIDN / 4];  // 12 KB, row-major [s][j]
    __shared__ float b1s[HIDN];
    __shared__ float w2s[HIDN * 2];
    __shared__ float b2s[2];
    for (int i = threadIdx.x; i < SS * HIDN / 4; i += 256)
        w1s[i] = reinterpret_cast<const float4*>(W1)[i];
    if (threadIdx.x < HIDN) b1s[threadIdx.x] = b1[threadIdx.x];
    if (threadIdx.x < 2 * HIDN) w2s[threadIdx.x] = W2[threadIdx.x];
    if (threadIdx.x < 2) b2s[threadIdx.x] = b2[threadIdx.x];
    __syncthreads();

    int r = blockIdx.x * 256 + threadIdx.x;
    if (r >= BSZ * KK) return;
    int b = r / KK;
    int node = krig_idx[r];
    const float4* yrow = reinterpret_cast<const float4*>(y + (size_t)(b * NN + node) * SS);

    float h[HIDN];
#pragma unroll
    for (int j = 0; j < HIDN; ++j) h[j] = b1s[j];
#pragma unroll
    for (int s4 = 0; s4 < F4PR; ++s4) {
        float4 v = yrow[s4];
        float vv[4] = {v.x, v.y, v.z, v.w};
        const float4* wbase = &w1s[s4 * 4 * (HIDN / 4)];
#pragma unroll
        for (int q = 0; q < 4; ++q) {
#pragma unroll
            for (int j4 = 0; j4 < HIDN / 4; ++j4) {
                float4 w = wbase[q * (HIDN / 4) + j4];
                h[j4 * 4 + 0] += vv[q] * w.x;
                h[j4 * 4 + 1] += vv[q] * w.y;
                h[j4 * 4 + 2] += vv[q] * w.z;
                h[j4 * 4 + 3] += vv[q] * w.w;
            }
        }
    }
    float l0 = b2s[0], l1 = b2s[1];
#pragma unroll
    for (int j = 0; j < HIDN; ++j) {
        float hr = fmaxf(h[j], 0.0f);
        l0 += hr * w2s[j * 2 + 0];
        l1 += hr * w2s[j * 2 + 1];
    }
    float g0 = gumbel[r * 2 + 0], g1 = gumbel[r * 2 + 1];
    // straight-through hard gumbel: forward value is exactly one-hot {0,1}
    int on = (l1 + g1 > l0 + g0);
    // gate==0 -> whole output row is exactly zero; encode -2 (no mask/y read later)
    flag2[offs[b] + node] = make_int2(on ? (b * NN + node) : -2, r);
}

// ------- kernel 3: fused single-pass output; per-row tri-state descriptor ----------
__global__ __launch_bounds__(256) void fuse_kernel(
    const vf4* __restrict__ x4, const vf4* __restrict__ y4,
    const vf4* __restrict__ mask4, const int2* __restrict__ flag2,
    vf4* __restrict__ out4) {
    const int t0 = blockIdx.x * (256 * NSLOT) + threadIdx.x;  // contiguous 32 KB/block

    int2 fg[NSLOT];
    // phase 1: all descriptor loads in flight (8 independent)
#pragma unroll
    for (int k = 0; k < NSLOT; ++k) {
        int idx = t0 + k * 256;
        fg[k] = flag2[idx / F4PR];
    }
    // phase 2: value loads (copy path needs no div; kriged path ~10% of slots)
    vf4 xv[NSLOT];
#pragma unroll
    for (int k = 0; k < NSLOT; ++k) {
        int idx = t0 + k * 256;
        int code = fg[k].x;
        vf4 v = (vf4)(0.0f);
        if (code == -1) {
            v = x4[idx];                       // 80% of rows: straight copy
        } else if (code >= 0) {
            int row = idx / F4PR;
            int c = idx - row * F4PR;
            vf4 m = mask4[fg[k].y * F4PR + c];
            v = m * y4[code * F4PR + c];       // gate==1 folded (exactly 1.0)
        }
        xv[k] = v;                             // code==-2: exact zeros
    }
    // phase 3: nontemporal stores (write-once stream, don't pollute L2/L3)
#pragma unroll
    for (int k = 0; k < NSLOT; ++k) {
        int idx = t0 + k * 256;
        __builtin_nontemporal_store(xv[k], out4 + idx);
    }
}

extern "C" void kernel_launch(void* const* d_in, const int* in_sizes, int n_in,
                              void* d_out, int out_size, void* d_ws, size_t ws_size,
                              hipStream_t stream) {
    const float* x      = (const float*)d_in[0];
    const float* y      = (const float*)d_in[1];
    const float* W1     = (const float*)d_in[2];
    const float* b1     = (const float*)d_in[3];
    const float* W2     = (const float*)d_in[4];
    const float* b2     = (const float*)d_in[5];
    const float* mask   = (const float*)d_in[6];
    const float* gumbel = (const float*)d_in[7];
    const int* krig_idx = (const int*)d_in[8];
    const int* idx_of_node = (const int*)d_in[9];
    float* out = (float*)d_out;

    int* offs = (int*)d_ws;                          // 512 ints
    int2* flag2 = (int2*)(offs + BSZ);               // 256000 int2 (2 MB), 8B-aligned

    prep_kernel<<<128, 512, 0, stream>>>(idx_of_node, offs,
                                         reinterpret_cast<int4*>(flag2));

    int rows = BSZ * KK;
    gate_kernel<<<(rows + 255) / 256, 256, 0, stream>>>(
        y, W1, b1, W2, b2, gumbel, krig_idx, offs, flag2);

    fuse_kernel<<<FUSE_BLOCKS, 256, 0, stream>>>(
        reinterpret_cast<const vf4*>(x), reinterpret_cast<const vf4*>(y),
        reinterpret_cast<const vf4*>(mask), flag2,
        reinterpret_cast<vf4*>(out));
}